// Round 1
// baseline (83.807 us; speedup 1.0000x reference)
//
#include <hip/hip_runtime.h>
#include <math.h>

#define NC 5
#define NBASIS (NC + 1)

struct BMat { float b[2 * NC][NBASIS]; };

// Reproduce numpy.linalg.svd(L)'s null-space basis (rows nC-1.. of Vt).
// LAPACK dgesdd with M=4, N=10, JOBZ='A' takes the "N >> M" path:
// LQ-factorize L (dgelqf), generate full Q (dorglq); rows M..N-1 of Vt are
// rows M..N-1 of Q, i.e. column c of basis = H1 H2 H3 H4 e_{M+c}.
// We replicate dgelqf/dorgl2 in double precision (rounding diffs ~1e-16,
// irrelevant after the float32 cast).
static BMat compute_basis() {
    const int m = NC - 1;      // 4
    const int n = 2 * NC;      // 10
    double A[NC - 1][2 * NC];
    for (int r = 0; r < m; ++r)
        for (int c = 0; c < n; ++c) A[r][c] = 0.0;
    for (int k = 1; k < NC; ++k) {
        double xk = (double)k / (double)NC;
        int i = k - 1;
        A[i][2 * i]     = xk;   A[i][2 * i + 1] = 1.0;
        A[i][2 * i + 2] = -xk;  A[i][2 * i + 3] = -1.0;
    }
    double tau[NC - 1];
    for (int i = 0; i < m; ++i) {
        double alpha = A[i][i];
        double xs = 0.0;
        for (int j = i + 1; j < n; ++j) xs += A[i][j] * A[i][j];
        double xnorm = sqrt(xs);
        if (xnorm == 0.0) { tau[i] = 0.0; continue; }
        double beta = (alpha >= 0.0 ? -1.0 : 1.0) * sqrt(alpha * alpha + xs);
        tau[i] = (beta - alpha) / beta;
        double inv = 1.0 / (alpha - beta);
        for (int j = i + 1; j < n; ++j) A[i][j] *= inv;
        A[i][i] = beta;
        // apply H(i) from the right to rows i+1..m-1
        for (int r = i + 1; r < m; ++r) {
            double dot = A[r][i];
            for (int j = i + 1; j < n; ++j) dot += A[r][j] * A[i][j];
            dot *= tau[i];
            A[r][i] -= dot;
            for (int j = i + 1; j < n; ++j) A[r][j] -= dot * A[i][j];
        }
    }
    BMat B;
    for (int c = 0; c < NBASIS; ++c) {
        double v[2 * NC];
        for (int r = 0; r < n; ++r) v[r] = 0.0;
        v[m + c] = 1.0;
        for (int i = m - 1; i >= 0; --i) {   // v := H(i) v
            double dot = v[i];
            for (int j = i + 1; j < n; ++j) dot += A[i][j] * v[j];
            dot *= tau[i];
            v[i] -= dot;
            for (int j = i + 1; j < n; ++j) v[j] -= dot * A[i][j];
        }
        for (int r = 0; r < n; ++r) B.b[r][c] = (float)v[r];
    }
    return B;
}

__device__ __forceinline__ void cpab_one(float y, const float* __restrict__ A,
                                         float& w_out, float& lj_out) {
#pragma clang fp contract(off)
    const float EPS = 1e-10f;
    const float BIG = 1e10f;
    float xx = y;
    float t_rem = 1.0f;
    float lj = 0.0f;
#pragma unroll 1
    for (int it = 0; it < NC + 1; ++it) {
        float f = floorf(xx * 5.0f);
        int c = (int)f;
        c = c < 0 ? 0 : (c > NC - 1 ? NC - 1 : c);
        float ac = A[2 * c];
        float bc = A[2 * c + 1];
        float v = ac * xx + bc;
        bool pos = (v >= 0.0f);
        int ct = pos ? (c + 1) : c;
        float xb = (float)ct / 5.0f;                 // f32 division, like reference
        bool at_edge = pos ? (c == NC - 1) : (c == 0);
        float vb = ac * xb + bc;
        float v_safe = (fabsf(v) > EPS) ? v : 1.0f;
        float a_safe = (fabsf(ac) > EPS) ? ac : 1.0f;
        float ratio = vb / v_safe;
        float t_hit;
        if (fabsf(ac) > EPS)
            t_hit = logf(ratio > EPS ? ratio : 1.0f) / a_safe;
        else
            t_hit = (xb - xx) / v_safe;
        bool valid = (fabsf(v) > EPS) && (ratio > EPS) && (!at_edge);
        if (!valid) t_hit = BIG;
        bool cross = (t_hit < t_rem);
        float t_step = cross ? t_hit : t_rem;
        float e = expm1f(ac * t_step);
        float x_flow = (fabsf(ac) > EPS) ? (xx + (v * e) / a_safe)
                                         : (xx + v * t_step);
        xx = cross ? xb : x_flow;
        lj = lj + ac * t_step;
        t_rem = t_rem - t_step;
        if (!cross) break;   // matches reference's `done` latch
    }
    w_out = xx;
    lj_out = lj;
}

__global__ __launch_bounds__(256) void cpab_kernel(
    const float* __restrict__ x, const float* __restrict__ theta,
    const float* __restrict__ pa, const float* __restrict__ pb,
    const float* __restrict__ pc, const float* __restrict__ pd,
    float* __restrict__ out, int N, BMat Bm)
{
#pragma clang fp contract(off)
    __shared__ float sA[2 * NC];
    __shared__ float sAff[4];
    if (threadIdx.x < 2 * NC) {
        float acc = 0.0f;
#pragma unroll
        for (int j = 0; j < NBASIS; ++j) acc += Bm.b[threadIdx.x][j] * theta[j];
        sA[threadIdx.x] = acc;
    }
    if (threadIdx.x == 2 * NC) {
        sAff[0] = pa[0]; sAff[1] = pb[0]; sAff[2] = pc[0]; sAff[3] = pd[0];
    }
    __syncthreads();
    float Aloc[2 * NC];
#pragma unroll
    for (int i = 0; i < 2 * NC; ++i) Aloc[i] = sA[i];
    float aff_a = sAff[0], aff_b = sAff[1], aff_c = sAff[2], aff_d = sAff[3];
    float ljadd = logf(aff_a * aff_c);   // == 0 exactly for aff_a*aff_c == 1

    int idx = blockIdx.x * blockDim.x + threadIdx.x;
    int nv = N >> 2;
    if (idx >= nv) return;
    const float4* x4 = (const float4*)x;
    float4 xv = x4[idx];
    float xin[4] = {xv.x, xv.y, xv.z, xv.w};
    float z[4], l[4];
#pragma unroll
    for (int u = 0; u < 4; ++u) {
        float y = aff_a * xin[u] + aff_b;
        float w, lj;
        cpab_one(y, Aloc, w, lj);
        z[u] = aff_c * w + aff_d;
        l[u] = lj + ljadd;
    }
    float4* oz = (float4*)out;
    float4* ol = (float4*)(out + N);
    oz[idx] = make_float4(z[0], z[1], z[2], z[3]);
    ol[idx] = make_float4(l[0], l[1], l[2], l[3]);
}

extern "C" void kernel_launch(void* const* d_in, const int* in_sizes, int n_in,
                              void* d_out, int out_size, void* d_ws, size_t ws_size,
                              hipStream_t stream) {
    const float* x     = (const float*)d_in[0];
    const float* theta = (const float*)d_in[1];
    const float* pa    = (const float*)d_in[2];
    const float* pb    = (const float*)d_in[3];
    const float* pc    = (const float*)d_in[4];
    const float* pd    = (const float*)d_in[5];
    float* out = (float*)d_out;
    int N = in_sizes[0];

    BMat Bm = compute_basis();   // host, double precision, deterministic

    int nv = N >> 2;             // N = 4194304 is divisible by 4
    int block = 256;
    int grid = (nv + block - 1) / block;
    cpab_kernel<<<grid, block, 0, stream>>>(x, theta, pa, pb, pc, pd, out, N, Bm);
}

// Round 2
// 19.469 us; speedup vs baseline: 4.3046x; 4.3046x over previous
//
#include <hip/hip_runtime.h>
#include <math.h>

#define NC 5
#define NBASIS (NC + 1)
#define EPSF 1e-10f
#define BIGF 1e10f

struct BMat { float b[2 * NC][NBASIS]; };

// Reproduce numpy.linalg.svd(L)'s null-space basis (rows nC-1.. of Vt).
// LAPACK dgesdd (M=4 << N=10) LQ path: basis col c = H1 H2 H3 H4 e_{M+c}.
static BMat compute_basis() {
    const int m = NC - 1;      // 4
    const int n = 2 * NC;      // 10
    double A[NC - 1][2 * NC];
    for (int r = 0; r < m; ++r)
        for (int c = 0; c < n; ++c) A[r][c] = 0.0;
    for (int k = 1; k < NC; ++k) {
        double xk = (double)k / (double)NC;
        int i = k - 1;
        A[i][2 * i]     = xk;   A[i][2 * i + 1] = 1.0;
        A[i][2 * i + 2] = -xk;  A[i][2 * i + 3] = -1.0;
    }
    double tau[NC - 1];
    for (int i = 0; i < m; ++i) {
        double alpha = A[i][i];
        double xs = 0.0;
        for (int j = i + 1; j < n; ++j) xs += A[i][j] * A[i][j];
        double xnorm = sqrt(xs);
        if (xnorm == 0.0) { tau[i] = 0.0; continue; }
        double beta = (alpha >= 0.0 ? -1.0 : 1.0) * sqrt(alpha * alpha + xs);
        tau[i] = (beta - alpha) / beta;
        double inv = 1.0 / (alpha - beta);
        for (int j = i + 1; j < n; ++j) A[i][j] *= inv;
        A[i][i] = beta;
        for (int r = i + 1; r < m; ++r) {
            double dot = A[r][i];
            for (int j = i + 1; j < n; ++j) dot += A[r][j] * A[i][j];
            dot *= tau[i];
            A[r][i] -= dot;
            for (int j = i + 1; j < n; ++j) A[r][j] -= dot * A[i][j];
        }
    }
    BMat B;
    for (int c = 0; c < NBASIS; ++c) {
        double v[2 * NC];
        for (int r = 0; r < n; ++r) v[r] = 0.0;
        v[m + c] = 1.0;
        for (int i = m - 1; i >= 0; --i) {
            double dot = v[i];
            for (int j = i + 1; j < n; ++j) dot += A[i][j] * v[j];
            dot *= tau[i];
            v[i] -= dot;
            for (int j = i + 1; j < n; ++j) v[j] -= dot * A[i][j];
        }
        for (int r = 0; r < n; ++r) B.b[r][c] = (float)v[r];
    }
    return B;
}

// Per-point analytic evaluation using per-cell tables.
// sCA[c] = {a, b, knotL, knotR}
// sCW[c] = {tR (BIG if cell can't be fully traversed rightward),
//           ljR = a*tR, aF (0 if stuck-on-entry), vF = vL (0 if stuck)}
__device__ __forceinline__ void eval_one(float y,
                                         const float4* __restrict__ sCA,
                                         const float4* __restrict__ sCW,
                                         float& zo, float& lo) {
#pragma clang fp contract(off)
    float u = y * 5.0f;                       // bit-identical to reference
    int c = (int)floorf(u);
    c = c < 0 ? 0 : (c > NC - 1 ? NC - 1 : c);
    float4 A4 = sCA[c];
    float a = A4.x, b = A4.y;
    float v = a * y + b;                      // contract off: matches np order
    bool pos = (v >= 0.0f);
    float xb = pos ? A4.w : A4.z;
    bool at_edge = pos ? (c == NC - 1) : (c == 0);
    float vb = a * xb + b;
    bool vok = fabsf(v) > EPSF;
    float v_safe = vok ? v : 1.0f;
    float ratio = __fdividef(vb, v_safe);
    bool aok = fabsf(a) > EPSF;
    float a_safe = aok ? a : 1.0f;
    float lg = __logf(ratio > EPSF ? ratio : 1.0f);
    float t0 = aok ? __fdividef(lg, a_safe) : __fdividef(xb - y, v_safe);
    bool valid = vok && (ratio > EPSF) && (!at_edge);
    if (!valid) t0 = BIGF;
    bool cross0 = (t0 < 1.0f);

    // defaults: no crossing -> flow in start cell for full unit time
    float P = y, VP = v, AP = a, TT = 1.0f, LJ0 = 0.0f;
    if (cross0) {
        LJ0 = a * t0;
        if (!pos) {
            // leftward crossing: reference sticks at the knot (t_hit=0 loop)
            P = xb; VP = 0.0f; AP = 0.0f; TT = 0.0f;
        } else {
            // rightward walk over full-cell traverse times
            int j = c + 1;                    // pos && !at_edge => c <= 3
            float T = t0;
#pragma unroll
            for (int s = 0; s < 3; ++s) {
                float4 W = sCW[j];
                bool adv = (j < NC - 1) && (T + W.x < 1.0f);
                if (adv) { T += W.x; LJ0 += W.y; ++j; }
            }
            float4 Wf = sCW[j];
            float4 Af = sCA[j];
            P  = Af.z;                        // left knot of final cell
            VP = Wf.w;                        // entry velocity (0 if stuck)
            AP = Wf.z;                        // slope for flow (0 if stuck)
            TT = 1.0f - T;
        }
    }
    float at = AP * TT;
    bool apok = fabsf(AP) > EPSF;
    float e = __expf(at) - 1.0f;              // expm1: exp-1 except tiny arg
    float pm = at * (1.0f + at * (0.5f + at * 0.16666667f));
    if (fabsf(at) < 0.03f) e = pm;
    float delta = apok ? __fdividef(VP * e, AP) : (VP * TT);
    zo = P + delta;
    lo = LJ0 + at;
}

__global__ __launch_bounds__(256) void cpab_kernel(
    const float* __restrict__ x, const float* __restrict__ theta,
    const float* __restrict__ pa, const float* __restrict__ pb,
    const float* __restrict__ pc, const float* __restrict__ pd,
    float* __restrict__ out, int N, BMat Bm)
{
#pragma clang fp contract(off)
    __shared__ float sA[2 * NC];
    __shared__ float sAff[4];
    __shared__ float4 sCA[NC];
    __shared__ float4 sCW[NC];
    int tid = threadIdx.x;
    if (tid < 2 * NC) {
        float acc = 0.0f;
#pragma unroll
        for (int j = 0; j < NBASIS; ++j) acc += Bm.b[tid][j] * theta[j];
        sA[tid] = acc;
    }
    if (tid == 2 * NC) {
        sAff[0] = pa[0]; sAff[1] = pb[0]; sAff[2] = pc[0]; sAff[3] = pd[0];
    }
    __syncthreads();
    if (tid < NC) {
        int c = tid;
        float a = sA[2 * c], b = sA[2 * c + 1];
        float kL = (float)c / 5.0f;
        float kR = (float)(c + 1) / 5.0f;
        sCA[c] = make_float4(a, b, kL, kR);
        float vL = a * kL + b;                // bit-identical to per-iter ref
        float vR = a * kR + b;
        bool pos = (vL >= 0.0f);
        bool vok = fabsf(vL) > EPSF;
        float v_safe = vok ? vL : 1.0f;
        float ratio = vR / v_safe;            // precise ops here (runs once)
        bool aok = fabsf(a) > EPSF;
        float a_safe = aok ? a : 1.0f;
        float tR = aok ? (logf(ratio > EPSF ? ratio : 1.0f) / a_safe)
                       : ((kR - kL) / v_safe);
        bool valid = vok && (ratio > EPSF) && (c != NC - 1) && pos;
        if (!valid) tR = BIGF;
        float ljR = a * tR;
        float aF = pos ? a : 0.0f;            // entering with v<0 => stuck
        float vF = pos ? vL : 0.0f;
        sCW[c] = make_float4(tR, ljR, aF, vF);
    }
    __syncthreads();

    float aff_a = sAff[0], aff_b = sAff[1], aff_c = sAff[2], aff_d = sAff[3];
    float ljadd = logf(aff_a * aff_c);        // exactly 0 for identity affine

    int idx = blockIdx.x * blockDim.x + tid;
    int nv = N >> 2;
    if (idx >= nv) return;
    float4 xv = ((const float4*)x)[idx];
    float xi[4] = {xv.x, xv.y, xv.z, xv.w};
    float z[4], l[4];
#pragma unroll
    for (int q = 0; q < 4; ++q) {
        float y = aff_a * xi[q] + aff_b;
        float w, lj;
        eval_one(y, sCA, sCW, w, lj);
        z[q] = aff_c * w + aff_d;
        l[q] = lj + ljadd;
    }
    ((float4*)out)[idx] = make_float4(z[0], z[1], z[2], z[3]);
    ((float4*)(out + N))[idx] = make_float4(l[0], l[1], l[2], l[3]);
}

extern "C" void kernel_launch(void* const* d_in, const int* in_sizes, int n_in,
                              void* d_out, int out_size, void* d_ws, size_t ws_size,
                              hipStream_t stream) {
    const float* x     = (const float*)d_in[0];
    const float* theta = (const float*)d_in[1];
    const float* pa    = (const float*)d_in[2];
    const float* pb    = (const float*)d_in[3];
    const float* pc    = (const float*)d_in[4];
    const float* pd    = (const float*)d_in[5];
    float* out = (float*)d_out;
    int N = in_sizes[0];

    BMat Bm = compute_basis();

    int nv = N >> 2;
    int block = 256;
    int grid = (nv + block - 1) / block;
    cpab_kernel<<<grid, block, 0, stream>>>(x, theta, pa, pb, pc, pd, out, N, Bm);
}